// Round 8
// baseline (2888.663 us; speedup 1.0000x reference)
//
#include <hip/hip_runtime.h>

// APPNP propagation: h <- (1-alpha) * A @ h + alpha * x, K=10 steps.
// R8 = R6 with ext_vector_type fix (HIP int4/uint4 are structs; the
// __builtin_nontemporal_* builtins only take native clang vectors).
// Feature-sliced SpMM (8 slices x 16 feats, 3.2 MB/slice pinned per-XCD-L2
// via blockIdx&7), latency-pipelined:
//  - software-pipelined nt csr prefetch (batch i+1 issued before batch i's FMAs)
//  - wave = 32 rows x 2 lanes, 16 B gathers (8 feats/lane)
//  - CSR rows even-padded (16 B-aligned starts, zero-weight pads); zeroed tail
//    absorbs prefetch overshoot
//  - full 32 B/row contiguous stores
// R5 post-mortem: serial csr(HBM,nt)->gather chain, ~23% VALU, latency-bound.

#define N_NODES 100000
#define N_EDGES 1600000
#define D_FEAT  128
#define ALPHA   0.1f
#define K_STEPS 10

#define SCAN_ELEMS 512
#define SCAN_NBLK  ((N_NODES + SCAN_ELEMS - 1) / SCAN_ELEMS)  // 196

#define NSLICE 8
#define WAVES_PER_SLICE 1024
#define SLICE_BLOCKS (NSLICE * WAVES_PER_SLICE / 4)  // 2048 blocks x 4 waves
#define N_GRP (N_NODES / 32)                         // 3125 (exact)
#define CSR_CAP (N_EDGES + N_NODES + 64)             // even-padding + overshoot tail

typedef __attribute__((ext_vector_type(2))) float    f32x2;
typedef __attribute__((ext_vector_type(4))) float    f32x4;
typedef __attribute__((ext_vector_type(4))) int      i32x4;
typedef __attribute__((ext_vector_type(4))) unsigned u32x4;

static __device__ __forceinline__ float bf2f(unsigned u16) {
    return __uint_as_float(u16 << 16);
}
static __device__ __forceinline__ unsigned f2bf(float f) {
    unsigned u = __float_as_uint(f);
    return (u + 0x7fffu + ((u >> 16) & 1u)) >> 16;  // round-to-nearest-even
}

// ---------- CSR build (rows even-padded so each row starts 16 B-aligned) ----------

__global__ __launch_bounds__(256) void hist_kernel(const int* __restrict__ rows,
                                                   int* __restrict__ deg) {
    int e = blockIdx.x * 256 + threadIdx.x;
    if (e < N_EDGES) atomicAdd(&deg[rows[e]], 1);
}

__global__ __launch_bounds__(256) void scan_partial(const int* __restrict__ deg,
                                                    int* __restrict__ partial) {
    __shared__ int s[256];
    int b = blockIdx.x, t = threadIdx.x;
    int i0 = b * SCAN_ELEMS + t * 2;
    int v0 = (i0 < N_NODES) ? deg[i0] : 0;
    int v1 = (i0 + 1 < N_NODES) ? deg[i0 + 1] : 0;
    v0 += v0 & 1;  // round each row's slot count up to even
    v1 += v1 & 1;
    s[t] = v0 + v1;
    __syncthreads();
    for (int off = 128; off > 0; off >>= 1) {
        if (t < off) s[t] += s[t + off];
        __syncthreads();
    }
    if (t == 0) partial[b] = s[0];
}

__global__ __launch_bounds__(256) void scan_top(int* __restrict__ partial) {
    __shared__ int s[256];
    int t = threadIdx.x;
    s[t] = (t < SCAN_NBLK) ? partial[t] : 0;
    __syncthreads();
    for (int off = 1; off < 256; off <<= 1) {
        int v = (t >= off) ? s[t - off] : 0;
        __syncthreads();
        s[t] += v;
        __syncthreads();
    }
    if (t < SCAN_NBLK) partial[t] = (t == 0) ? 0 : s[t - 1];
}

// rowext[i] = {padded_beg (even), padded_beg + real_deg}; cursor[i] = padded_beg.
__global__ __launch_bounds__(256) void scan_final(int* __restrict__ deg_cursor,
                                                  const int* __restrict__ partial,
                                                  int2* __restrict__ rowext) {
    __shared__ int s[256];
    int b = blockIdx.x, t = threadIdx.x;
    int i0 = b * SCAN_ELEMS + t * 2;
    int d0 = (i0 < N_NODES) ? deg_cursor[i0] : 0;
    int d1 = (i0 + 1 < N_NODES) ? deg_cursor[i0 + 1] : 0;
    int v0 = d0 + (d0 & 1);
    int v1 = d1 + (d1 & 1);
    int pair = v0 + v1;
    s[t] = pair;
    __syncthreads();
    for (int off = 1; off < 256; off <<= 1) {
        int v = (t >= off) ? s[t - off] : 0;
        __syncthreads();
        s[t] += v;
        __syncthreads();
    }
    int ex = partial[b] + s[t] - pair;  // padded exclusive prefix of element 2t
    if (i0 < N_NODES) {
        rowext[i0] = make_int2(ex, ex + d0);
        deg_cursor[i0] = ex;
    }
    if (i0 + 1 < N_NODES) {
        rowext[i0 + 1] = make_int2(ex + v0, ex + v0 + d1);
        deg_cursor[i0 + 1] = ex + v0;
    }
}

__global__ __launch_bounds__(256) void scatter_kernel(const int* __restrict__ rows,
                                                      const int* __restrict__ cols,
                                                      const float* __restrict__ w,
                                                      int* __restrict__ cursor,
                                                      int2* __restrict__ csr) {
    int e = blockIdx.x * 256 + threadIdx.x;
    if (e < N_EDGES) {
        int pos = atomicAdd(&cursor[rows[e]], 1);
        int2 cw;
        cw.x = cols[e];
        cw.y = __float_as_int((1.0f - ALPHA) * w[e]);  // fold 0.9 into the weight
        csr[pos] = cw;
    }
}

// ---------- prep: x (node-major fp32) -> h0, xs (slice-major bf16, u32x4) ----------
// layout: slice s, node n, half j: u32x4 at (s*N + n)*2 + j = feats 16s+8j..+8

__global__ __launch_bounds__(256) void prep_x(const float4* __restrict__ x4,
                                              u32x4* __restrict__ h0,
                                              u32x4* __restrict__ xs) {
    int t = blockIdx.x * 256 + threadIdx.x;  // over N*16 u32x4s
    if (t >= N_NODES * 16) return;
    int n = t >> 4;
    int p = t & 15;  // p = s*2 + j
    const float4* src = x4 + (size_t)n * 32 + p * 2;
    float4 a = src[0], b = src[1];
    u32x4 h, xa;
    h.x = f2bf(a.x) | (f2bf(a.y) << 16);
    h.y = f2bf(a.z) | (f2bf(a.w) << 16);
    h.z = f2bf(b.x) | (f2bf(b.y) << 16);
    h.w = f2bf(b.z) | (f2bf(b.w) << 16);
    xa.x = f2bf(ALPHA * a.x) | (f2bf(ALPHA * a.y) << 16);
    xa.y = f2bf(ALPHA * a.z) | (f2bf(ALPHA * a.w) << 16);
    xa.z = f2bf(ALPHA * b.x) | (f2bf(ALPHA * b.y) << 16);
    xa.w = f2bf(ALPHA * b.z) | (f2bf(ALPHA * b.w) << 16);
    size_t o = ((size_t)(p >> 1) * N_NODES + n) * 2 + (p & 1);
    h0[o] = h;
    xs[o] = xa;
}

// ---------- propagation step: sliced, wave = 32 rows x 2 lanes, pipelined ----------

template <bool FINAL>
__global__ __launch_bounds__(256) void slice_spmm(const int2* __restrict__ rowext,
                                                  const i32x4* __restrict__ csr4,
                                                  const u32x4* __restrict__ xs,
                                                  const u32x4* __restrict__ hsrc,
                                                  u32x4* __restrict__ hdst,
                                                  f32x4* __restrict__ fout) {
    int s = blockIdx.x & 7;  // slice -> XCD via round-robin dispatch
    int wid = (blockIdx.x >> 3) * 4 + (threadIdx.x >> 6);  // 0..1023 within slice
    int lane = threadIdx.x & 63;
    int g = lane >> 1;   // row within group (0..31)
    int j = lane & 1;    // feature half (8 feats, 16 B)
    const u32x4* hs  = hsrc + (size_t)s * (N_NODES * 2);
    const u32x4* xss = xs   + (size_t)s * (N_NODES * 2);
    u32x4*       hd  = hdst + (size_t)s * (N_NODES * 2);

    for (int grp = wid; grp < N_GRP; grp += WAVES_PER_SLICE) {
        int r = grp * 32 + g;
        int2 be = rowext[r];   // 256 B contiguous across the wave
        int beg = be.x, end = be.y;
        int md = end - beg;    // pair-lanes (xor 1) already equal
        md = max(md, __shfl_xor(md, 2));
        md = max(md, __shfl_xor(md, 4));
        md = max(md, __shfl_xor(md, 8));
        md = max(md, __shfl_xor(md, 16));
        md = max(md, __shfl_xor(md, 32));
        int iters = (md + 7) >> 3;  // batches of 8 edges

        float acc[8];
#pragma unroll
        for (int i = 0; i < 8; ++i) acc[i] = 0.0f;

        const i32x4* cp = csr4 + (beg >> 1);  // beg is even -> 16 B aligned
        i32x4 cwA[4], cwB[4];
#pragma unroll
        for (int v = 0; v < 4; ++v) cwA[v] = __builtin_nontemporal_load(cp + v);

        int e0 = beg;
        for (int it = 0; it < iters; ++it) {
            // gathers for current batch (L2-resident slice, temporal)
            u32x4 hv[8];
            hv[0] = hs[(size_t)(unsigned)cwA[0].x * 2 + j];
            hv[1] = hs[(size_t)(unsigned)cwA[0].z * 2 + j];
            hv[2] = hs[(size_t)(unsigned)cwA[1].x * 2 + j];
            hv[3] = hs[(size_t)(unsigned)cwA[1].z * 2 + j];
            hv[4] = hs[(size_t)(unsigned)cwA[2].x * 2 + j];
            hv[5] = hs[(size_t)(unsigned)cwA[2].z * 2 + j];
            hv[6] = hs[(size_t)(unsigned)cwA[3].x * 2 + j];
            hv[7] = hs[(size_t)(unsigned)cwA[3].z * 2 + j];
            // prefetch next csr batch BEFORE consuming this one (hides HBM lat)
            cp += 4;
#pragma unroll
            for (int v = 0; v < 4; ++v) cwB[v] = __builtin_nontemporal_load(cp + v);

            float w[8];
            w[0] = (e0 + 0 < end) ? __int_as_float(cwA[0].y) : 0.0f;
            w[1] = (e0 + 1 < end) ? __int_as_float(cwA[0].w) : 0.0f;
            w[2] = (e0 + 2 < end) ? __int_as_float(cwA[1].y) : 0.0f;
            w[3] = (e0 + 3 < end) ? __int_as_float(cwA[1].w) : 0.0f;
            w[4] = (e0 + 4 < end) ? __int_as_float(cwA[2].y) : 0.0f;
            w[5] = (e0 + 5 < end) ? __int_as_float(cwA[2].w) : 0.0f;
            w[6] = (e0 + 6 < end) ? __int_as_float(cwA[3].y) : 0.0f;
            w[7] = (e0 + 7 < end) ? __int_as_float(cwA[3].w) : 0.0f;
#pragma unroll
            for (int u = 0; u < 8; ++u) {
                acc[0] += w[u] * bf2f(hv[u].x & 0xffffu);
                acc[1] += w[u] * bf2f(hv[u].x >> 16);
                acc[2] += w[u] * bf2f(hv[u].y & 0xffffu);
                acc[3] += w[u] * bf2f(hv[u].y >> 16);
                acc[4] += w[u] * bf2f(hv[u].z & 0xffffu);
                acc[5] += w[u] * bf2f(hv[u].z >> 16);
                acc[6] += w[u] * bf2f(hv[u].w & 0xffffu);
                acc[7] += w[u] * bf2f(hv[u].w >> 16);
            }
#pragma unroll
            for (int v = 0; v < 4; ++v) cwA[v] = cwB[v];
            e0 += 8;
        }

        u32x4 xv = __builtin_nontemporal_load(xss + (size_t)r * 2 + j);
        float o[8];
        o[0] = acc[0] + bf2f(xv.x & 0xffffu);
        o[1] = acc[1] + bf2f(xv.x >> 16);
        o[2] = acc[2] + bf2f(xv.y & 0xffffu);
        o[3] = acc[3] + bf2f(xv.y >> 16);
        o[4] = acc[4] + bf2f(xv.z & 0xffffu);
        o[5] = acc[5] + bf2f(xv.z >> 16);
        o[6] = acc[6] + bf2f(xv.w & 0xffffu);
        o[7] = acc[7] + bf2f(xv.w >> 16);

        if (FINAL) {
            // node-major fp32: row r, feats 16s+8j.. -> f32x4 idx r*32 + s*4 + j*2
            f32x4 f0, f1;
            f0.x = o[0]; f0.y = o[1]; f0.z = o[2]; f0.w = o[3];
            f1.x = o[4]; f1.y = o[5]; f1.z = o[6]; f1.w = o[7];
            size_t ob = (size_t)r * 32 + s * 4 + j * 2;
            __builtin_nontemporal_store(f0, fout + ob);
            __builtin_nontemporal_store(f1, fout + ob + 1);
        } else {
            u32x4 p;
            p.x = f2bf(o[0]) | (f2bf(o[1]) << 16);
            p.y = f2bf(o[2]) | (f2bf(o[3]) << 16);
            p.z = f2bf(o[4]) | (f2bf(o[5]) << 16);
            p.w = f2bf(o[6]) | (f2bf(o[7]) << 16);
            __builtin_nontemporal_store(p, hd + (size_t)r * 2 + j);
        }
    }
}

// ---------- R0 fallback (atomic path) if ws too small ----------

__global__ __launch_bounds__(256) void init_step(const float4* __restrict__ x,
                                                 float4* __restrict__ dst, int n4) {
    int i = blockIdx.x * 256 + threadIdx.x;
    if (i < n4) {
        float4 v = x[i];
        dst[i] = make_float4(ALPHA * v.x, ALPHA * v.y, ALPHA * v.z, ALPHA * v.w);
    }
}

__global__ __launch_bounds__(256) void edge_scatter(const int* __restrict__ rows,
                                                    const int* __restrict__ cols,
                                                    const float* __restrict__ w,
                                                    const float* __restrict__ h,
                                                    float* __restrict__ dst) {
    unsigned t = blockIdx.x * 256u + threadIdx.x;
    unsigned e = t >> 5;
    unsigned l = t & 31u;
    if (e >= N_EDGES) return;
    int r = rows[e];
    int c = cols[e];
    float we = (1.0f - ALPHA) * w[e];
    const float4* hc = (const float4*)(h + (size_t)c * D_FEAT);
    float4 v = hc[l];
    float* dr = dst + (size_t)r * D_FEAT + (size_t)l * 4;
    unsafeAtomicAdd(dr + 0, we * v.x);
    unsafeAtomicAdd(dr + 1, we * v.y);
    unsafeAtomicAdd(dr + 2, we * v.z);
    unsafeAtomicAdd(dr + 3, we * v.w);
}

extern "C" void kernel_launch(void* const* d_in, const int* in_sizes, int n_in,
                              void* d_out, int out_size, void* d_ws, size_t ws_size,
                              hipStream_t stream) {
    const float* x  = (const float*)d_in[0];
    const int*   ei = (const int*)d_in[1];  // [2, E] flat: rows then cols
    const float* ev = (const float*)d_in[2];
    const int* rows = ei;
    const int* cols = ei + N_EDGES;
    float* out = (float*)d_out;

    size_t off = 0;
    auto take = [&](size_t bytes) {
        size_t o = off;
        off = (off + bytes + 15) & ~(size_t)15;
        return o;
    };
    size_t o_ha      = take((size_t)N_NODES * D_FEAT * 2);  // 25.6 MB slice-major A
    size_t o_hb      = take((size_t)N_NODES * D_FEAT * 2);  // 25.6 MB slice-major B
    size_t o_xs      = take((size_t)N_NODES * D_FEAT * 2);  // 25.6 MB xs = 0.1x
    size_t o_rowext  = take((size_t)N_NODES * 8);
    size_t o_cursor  = take((size_t)N_NODES * 4);
    size_t o_partial = take((size_t)SCAN_NBLK * 4);
    size_t o_csr     = take((size_t)CSR_CAP * 8);           // 13.6 MB padded CSR
    size_t need_slice = off;

    const int edge_blocks_1t = (N_EDGES + 255) / 256;  // 6250

    char* wsb = (char*)d_ws;
    if (ws_size >= need_slice) {
        u32x4* hA      = (u32x4*)(wsb + o_ha);
        u32x4* hB      = (u32x4*)(wsb + o_hb);
        u32x4* xs      = (u32x4*)(wsb + o_xs);
        int2*  rowext  = (int2*)(wsb + o_rowext);
        int*   cursor  = (int*)(wsb + o_cursor);
        int*   partial = (int*)(wsb + o_partial);
        int2*  csr     = (int2*)(wsb + o_csr);

        // CSR build (every call — ws re-poisoned by harness)
        (void)hipMemsetAsync(cursor, 0, (size_t)N_NODES * 4, stream);
        (void)hipMemsetAsync(csr, 0, (size_t)CSR_CAP * 8, stream);  // zero pads/tail
        hist_kernel<<<edge_blocks_1t, 256, 0, stream>>>(rows, cursor);
        scan_partial<<<SCAN_NBLK, 256, 0, stream>>>(cursor, partial);
        scan_top<<<1, 256, 0, stream>>>(partial);
        scan_final<<<SCAN_NBLK, 256, 0, stream>>>(cursor, partial, rowext);
        scatter_kernel<<<edge_blocks_1t, 256, 0, stream>>>(rows, cols, ev, cursor, csr);
        prep_x<<<(N_NODES * 16 + 255) / 256, 256, 0, stream>>>((const float4*)x, hA, xs);

        const i32x4* csr4 = (const i32x4*)csr;
        for (int k = 0; k < K_STEPS - 1; ++k) {
            const u32x4* src = (k & 1) ? hB : hA;
            u32x4* dst = (k & 1) ? hA : hB;
            slice_spmm<false><<<SLICE_BLOCKS, 256, 0, stream>>>(rowext, csr4, xs,
                                                                src, dst, (f32x4*)out);
        }
        // k=9 (odd): src = hB, write fp32 node-major to d_out
        slice_spmm<true><<<SLICE_BLOCKS, 256, 0, stream>>>(rowext, csr4, xs,
                                                           hB, hA, (f32x4*)out);
    } else {
        float* wsf = (float*)d_ws;
        const int n4 = N_NODES * D_FEAT / 4;
        const int init_blocks = (n4 + 255) / 256;
        const int edge_blocks = (N_EDGES * 32 + 255) / 256;
        for (int k = 0; k < K_STEPS; ++k) {
            const float* src = (k == 0) ? x : ((k & 1) ? wsf : out);
            float* dst = (k & 1) ? out : wsf;
            init_step<<<init_blocks, 256, 0, stream>>>((const float4*)x, (float4*)dst, n4);
            edge_scatter<<<edge_blocks, 256, 0, stream>>>(rows, cols, ev, src, dst);
        }
    }
}